// Round 12
// baseline (126.998 us; speedup 1.0000x reference)
//
#include <hip/hip_runtime.h>
#include <hip/hip_bf16.h>
#include <math.h>

#define EPS 1e-6f
#define N 64          // INPUT_SIZE == NUM_LEAVES
#define NLAYERS 63
#define SINK_ITERS 20
#define LOG2E 1.4426950408889634f

typedef __attribute__((ext_vector_type(8))) short bf16x8;   // 8 bf16 = 4 VGPRs
typedef __attribute__((ext_vector_type(4))) float f32x4;    // MFMA C/D

// Hardware transcendentals: single v_log_f32 / v_exp_f32. Inputs clamped to
// [EPS, 1-EPS] (normal range) -> no denormal/edge fixup needed.
__device__ __forceinline__ float fast_log2(float v) {
#if __has_builtin(__builtin_amdgcn_logf)
  return __builtin_amdgcn_logf(v);
#else
  return log2f(v);
#endif
}
__device__ __forceinline__ float fast_exp2(float v) {
#if __has_builtin(__builtin_amdgcn_exp2f)
  return __builtin_amdgcn_exp2f(v);
#else
  return exp2f(v);
#endif
}

// fp32 -> bf16 round-to-nearest-even (bit pattern in ushort)
__device__ __forceinline__ unsigned short f2bf(float f) {
  unsigned int u = __float_as_uint(f);
  return (unsigned short)((u + 0x7FFFu + ((u >> 16) & 1u)) >> 16);
}
__device__ __forceinline__ float bf2f(unsigned short s) {
  return __uint_as_float(((unsigned int)s) << 16);
}

__device__ __forceinline__ bf16x8 pack8(float4 a, float4 b) {
  union { unsigned short us[8]; bf16x8 v; } u;
  u.us[0] = f2bf(a.x); u.us[1] = f2bf(a.y);
  u.us[2] = f2bf(a.z); u.us[3] = f2bf(a.w);
  u.us[4] = f2bf(b.x); u.us[5] = f2bf(b.y);
  u.us[6] = f2bf(b.z); u.us[7] = f2bf(b.w);
  return u.v;
}

// ---------------------------------------------------------------------------
// Kernel 1: Sinkhorn (scaling-vector form, single wave) + P -> MFMA B-fragment
// precompute (bf16) + per-layer scan constants. (Validated R8-R11.)
// B-frag for mfma_f32_16x16x32_bf16: lane l holds
// B[k = s*32 + (l>>4)*8 + j][n = t*16 + (l&15)], j=0..7.
// ---------------------------------------------------------------------------
__global__ __launch_bounds__(64) void sinkhorn_kernel(
    const float* __restrict__ logits,
    const float* __restrict__ weights,
    const float* __restrict__ biases,
    unsigned short* __restrict__ Pfrag,  // [8][64][8] bf16
    float* __restrict__ layers) {        // [63][8]: w0,w1,e0,e1,cl,cg,a,mode
  __shared__ float T[64 * 65 + 128];
  const int l = threadIdx.x;

  float K[64];
  {
    const float4* lr = (const float4*)(logits + (l << 6));
    #pragma unroll
    for (int q = 0; q < 16; ++q) {
      float4 t = lr[q];
      K[4*q+0] = fast_exp2(t.x * LOG2E);
      K[4*q+1] = fast_exp2(t.y * LOG2E);
      K[4*q+2] = fast_exp2(t.z * LOG2E);
      K[4*q+3] = fast_exp2(t.w * LOG2E);
    }
  }
  #pragma unroll
  for (int j = 0; j < 64; ++j) T[l * 65 + j] = K[j];
  __syncthreads();
  float KT[64];
  #pragma unroll
  for (int k = 0; k < 64; ++k) KT[k] = T[k * 65 + l];
  __syncthreads();

  float* Uv = &T[64 * 65];        // 16B-aligned
  float* Vv = &T[64 * 65 + 64];   // 16B-aligned
  const float4* Uv4 = (const float4*)Uv;
  const float4* Vv4 = (const float4*)Vv;
  Vv[l] = 1.0f;
  __syncthreads();

  float u = 1.0f;
  for (int it = 0; it < SINK_ITERS; ++it) {
    float s0 = 0.f, s1 = 0.f, s2 = 0.f, s3 = 0.f;
    #pragma unroll
    for (int q = 0; q < 16; ++q) {
      float4 v = Vv4[q];
      s0 = fmaf(K[4*q+0], v.x, s0);
      s1 = fmaf(K[4*q+1], v.y, s1);
      s2 = fmaf(K[4*q+2], v.z, s2);
      s3 = fmaf(K[4*q+3], v.w, s3);
    }
    u = 1.0f / ((s0 + s1) + (s2 + s3));
    __syncthreads();
    Uv[l] = u;
    __syncthreads();
    float c0 = 0.f, c1 = 0.f, c2 = 0.f, c3 = 0.f;
    #pragma unroll
    for (int q = 0; q < 16; ++q) {
      float4 uu = Uv4[q];
      c0 = fmaf(KT[4*q+0], uu.x, c0);
      c1 = fmaf(KT[4*q+1], uu.y, c1);
      c2 = fmaf(KT[4*q+2], uu.z, c2);
      c3 = fmaf(KT[4*q+3], uu.w, c3);
    }
    float v = 1.0f / ((c0 + c1) + (c2 + c3));
    __syncthreads();
    Vv[l] = v;
    __syncthreads();
  }

  #pragma unroll
  for (int j = 0; j < 64; ++j) T[l * 65 + j] = u * K[j] * Vv[j];
  __syncthreads();

  #pragma unroll
  for (int s = 0; s < 2; ++s)
    #pragma unroll
    for (int t = 0; t < 4; ++t) {
      union { unsigned short us[8]; bf16x8 v; } buf;
      #pragma unroll
      for (int j = 0; j < 8; ++j)
        buf.us[j] = f2bf(T[(s*32 + ((l >> 4) << 3) + j) * 65 + t*16 + (l & 15)]);
      *(bf16x8*)(Pfrag + (((s*4 + t) * 64 + l) << 3)) = buf.v;
    }

  if (l < NLAYERS) {
    float w0 = weights[l];
    float w1 = 1.0f - w0;
    float a  = biases[l];
    float e0 = 0.f, e1 = 0.f, cl = 0.f, cg = 0.f, mode;
    if (fabsf(a - 0.5f) < EPS) {
      mode = 0.0f;
    } else {
      float ae;
      if (a < 0.5f) { mode = 2.0f; ae = fminf(fmaxf(1.0f - a, -1.0f + EPS), 2.0f - EPS); }
      else          { mode = 1.0f; ae = a; }
      float pp = sqrtf(3.0f / fmaxf(2.0f - ae, EPS)) - 1.0f;
      if (ae >= 0.75f) { cl = 0.0f;            cg = 1.0f; }
      else             { cl = 3.0f - 4.0f*ae;  cg = 4.0f*ae - 2.0f; }
      e0 = 2.0f * w0 * pp;
      e1 = 2.0f * w1 * pp;
    }
    float* Lr = layers + l * 8;
    Lr[0] = w0; Lr[1] = w1; Lr[2] = e0; Lr[3] = e1;
    Lr[4] = cl; Lr[5] = cg; Lr[6] = a;  Lr[7] = mode;
  }
}

// ---------------------------------------------------------------------------
// F step: register-only, wave-uniform branch, hardware log2/exp2.
// ---------------------------------------------------------------------------
__device__ __forceinline__ float F_step(float st, float leaf,
                                        const float* __restrict__ Lp) {
  float w0 = Lp[0], w1 = Lp[1], e0 = Lp[2], e1 = Lp[3];
  float cl = Lp[4], cg = Lp[5], av = Lp[6], mf = Lp[7];
  float xx = fminf(fmaxf(st,   EPS), 1.0f - EPS);
  float yy = fminf(fmaxf(leaf, EPS), 1.0f - EPS);
  float r;
  if (mf < 0.5f) {
    r = w0 * xx + w1 * yy;
  } else {
    if (mf > 1.5f) { xx = 1.0f - xx; yy = 1.0f - yy; }
    float lin = w0 * xx + w1 * yy;
    float g   = fast_exp2(e0 * fast_log2(xx) + e1 * fast_log2(yy));
    r = cl * lin + cg * g;
    if (mf > 1.5f) r = 1.0f - r;
  }
  return (r != r) ? av : r;   // NaN fallback to bias
}

// ---------------------------------------------------------------------------
// Kernel 2 (R12): single full-width GEMM pass + bf16 leaf buffer + one
// unbroken register-only F-chain.
//   - Swapped-operand MFMA (validated R11): mfma(Bf,Af) = (A.B)^T, lane l
//     reg r holds leaf lt*16+q*4+r of batch row rt*16+c.
//   - All 16 D-tiles packed to bf16 -> ds_write_b64 into Lv[256][68]
//     (stride 68 shorts = 136 B, 8B-aligned; 34.8 KB -> 4 blocks/CU).
//   - After GEMM Af/Bf die; chain holds 64 bf16 leaves in 32 VGPRs
//     (16x ds_read_b64, one lgkmcnt wait, then pure VALU).
//   - Zero barriers: wave w writes/reads only rows w*64..w*64+63.
//   - launch_bounds(256,4): peak ~90 regs < 128 cap -> 4 waves/SIMD.
// ---------------------------------------------------------------------------
__global__ __launch_bounds__(256, 4) void scan_kernel(
    const float* __restrict__ x,
    const unsigned short* __restrict__ Pfrag,
    const float* __restrict__ layers,
    float* __restrict__ out) {
  __shared__ unsigned short Lv[256 * 68];   // 34816 B
  const int tid = threadIdx.x;
  const int w = tid >> 6, l = tid & 63;
  const int q = l >> 4, c = l & 15;
  const size_t rowbase = (size_t)blockIdx.x << 8;   // 256 rows per block

  // ---- B fragments (Aop after swap): Pfrag, wave-uniform, L2-hot.
  bf16x8 Bf[2][4];
  #pragma unroll
  for (int s = 0; s < 2; ++s)
    #pragma unroll
    for (int t = 0; t < 4; ++t)
      Bf[s][t] = *(const bf16x8*)(Pfrag + (((s*4 + t) * 64 + l) << 3));

  // ---- A fragments (Bop after swap): transient per-tile gather from x.
  bf16x8 Af[4][2];
  #pragma unroll
  for (int i = 0; i < 4; ++i) {
    const float* rp = x + (rowbase + (w << 6) + (i << 4) + c) * 64 + (q << 3);
    float4 a0 = *(const float4*)(rp);
    float4 a1 = *(const float4*)(rp + 4);
    float4 b0 = *(const float4*)(rp + 32);
    float4 b1 = *(const float4*)(rp + 36);
    Af[i][0] = pack8(a0, a1);
    Af[i][1] = pack8(b0, b1);
  }

  // ---- full GEMM^T: 4 row-tiles x 4 leaf-tiles, D packed bf16 -> LDS.
  #pragma unroll
  for (int rt = 0; rt < 4; ++rt) {
    const int row = (w << 6) + (rt << 4) + c;     // block-local batch row
    #pragma unroll
    for (int lt = 0; lt < 4; ++lt) {
      f32x4 acc = {0.f, 0.f, 0.f, 0.f};
      acc = __builtin_amdgcn_mfma_f32_16x16x32_bf16(Bf[0][lt], Af[rt][0], acc, 0, 0, 0);
      acc = __builtin_amdgcn_mfma_f32_16x16x32_bf16(Bf[1][lt], Af[rt][1], acc, 0, 0, 0);
      union { unsigned short us[4]; unsigned long long u8; } pk;
      pk.us[0] = f2bf(acc[0]); pk.us[1] = f2bf(acc[1]);
      pk.us[2] = f2bf(acc[2]); pk.us[3] = f2bf(acc[3]);
      // leaf offset lt*16 + q*4; byte addr row*136 + (lt*16+q*4)*2: 8B-aligned
      *(unsigned long long*)&Lv[row * 68 + (lt << 4) + (q << 2)] = pk.u8;
    }
  }

  // ---- own row -> registers (16x ds_read_b64; wave-local DS ordering).
  union { unsigned long long u8[16]; unsigned short us[64]; } Lb;
  #pragma unroll
  for (int i = 0; i < 16; ++i)
    Lb.u8[i] = *(unsigned long long*)&Lv[tid * 68 + (i << 2)];

  // ---- one unbroken register-only F chain over 64 leaves.
  float st = bf2f(Lb.us[0]);
  #pragma unroll
  for (int j = 1; j < N; ++j)
    st = F_step(st, bf2f(Lb.us[j]), layers + (j - 1) * 8);

  out[rowbase + tid] = st;
}

// ---------------------------------------------------------------------------
extern "C" void kernel_launch(void* const* d_in, const int* in_sizes, int n_in,
                              void* d_out, int out_size, void* d_ws, size_t ws_size,
                              hipStream_t stream) {
  const float* x       = (const float*)d_in[0];
  const float* logits  = (const float*)d_in[1];
  const float* weights = (const float*)d_in[2];
  const float* biases  = (const float*)d_in[3];
  float* out = (float*)d_out;

  unsigned short* Pfrag = (unsigned short*)d_ws;              // 8 KB
  float* layers = (float*)((char*)d_ws + 8 * 64 * 8 * sizeof(unsigned short));

  const int batch = out_size;  // 262144

  hipLaunchKernelGGL(sinkhorn_kernel, dim3(1), dim3(64), 0, stream,
                     logits, weights, biases, Pfrag, layers);
  hipLaunchKernelGGL(scan_kernel, dim3(batch / 256), dim3(256), 0, stream,
                     x, Pfrag, layers, out);
}

// Round 13
// 122.076 us; speedup vs baseline: 1.0403x; 1.0403x over previous
//
#include <hip/hip_runtime.h>
#include <hip/hip_bf16.h>
#include <math.h>

#define EPS 1e-6f
#define N 64          // INPUT_SIZE == NUM_LEAVES
#define NLAYERS 63
#define SINK_ITERS 20
#define LOG2E 1.4426950408889634f

typedef __attribute__((ext_vector_type(8))) short bf16x8;   // 8 bf16 = 4 VGPRs
typedef __attribute__((ext_vector_type(4))) float f32x4;    // MFMA C/D

// Hardware transcendentals: single v_log_f32 / v_exp_f32. Inputs clamped to
// [EPS, 1-EPS] (normal range) -> no denormal/edge fixup needed.
__device__ __forceinline__ float fast_log2(float v) {
#if __has_builtin(__builtin_amdgcn_logf)
  return __builtin_amdgcn_logf(v);
#else
  return log2f(v);
#endif
}
__device__ __forceinline__ float fast_exp2(float v) {
#if __has_builtin(__builtin_amdgcn_exp2f)
  return __builtin_amdgcn_exp2f(v);
#else
  return exp2f(v);
#endif
}

// fp32 -> bf16 round-to-nearest-even (bit pattern in ushort)
__device__ __forceinline__ unsigned short f2bf(float f) {
  unsigned int u = __float_as_uint(f);
  return (unsigned short)((u + 0x7FFFu + ((u >> 16) & 1u)) >> 16);
}

__device__ __forceinline__ bf16x8 pack8(float4 a, float4 b) {
  union { unsigned short us[8]; bf16x8 v; } u;
  u.us[0] = f2bf(a.x); u.us[1] = f2bf(a.y);
  u.us[2] = f2bf(a.z); u.us[3] = f2bf(a.w);
  u.us[4] = f2bf(b.x); u.us[5] = f2bf(b.y);
  u.us[6] = f2bf(b.z); u.us[7] = f2bf(b.w);
  return u.v;
}

// ---------------------------------------------------------------------------
// Kernel 1: Sinkhorn (scaling-vector form, single wave) + P -> MFMA B-fragment
// precompute (bf16) + per-layer scan constants (BRANCHLESS encoding).
// Layer params [63][8]: w0, w1, e0, e1, cl, cg, a(nan-fallback), sgn.
//   sgn=+1/off=0 (no reflection), sgn=-1/off=1 (De Morgan reflection);
//   mode0 (|a-0.5|<eps) folds to cl=1, cg=0, e0=e1=0 (g==1 exactly).
// B-frag for mfma_f32_16x16x32_bf16: lane l holds
// B[k = s*32 + (l>>4)*8 + j][n = t*16 + (l&15)], j=0..7.
// ---------------------------------------------------------------------------
__global__ __launch_bounds__(64) void sinkhorn_kernel(
    const float* __restrict__ logits,
    const float* __restrict__ weights,
    const float* __restrict__ biases,
    unsigned short* __restrict__ Pfrag,  // [8][64][8] bf16
    float* __restrict__ layers) {        // [63][8]
  __shared__ float T[64 * 65 + 128];
  const int l = threadIdx.x;

  float K[64];
  {
    const float4* lr = (const float4*)(logits + (l << 6));
    #pragma unroll
    for (int q = 0; q < 16; ++q) {
      float4 t = lr[q];
      K[4*q+0] = fast_exp2(t.x * LOG2E);
      K[4*q+1] = fast_exp2(t.y * LOG2E);
      K[4*q+2] = fast_exp2(t.z * LOG2E);
      K[4*q+3] = fast_exp2(t.w * LOG2E);
    }
  }
  #pragma unroll
  for (int j = 0; j < 64; ++j) T[l * 65 + j] = K[j];
  __syncthreads();
  float KT[64];
  #pragma unroll
  for (int k = 0; k < 64; ++k) KT[k] = T[k * 65 + l];
  __syncthreads();

  float* Uv = &T[64 * 65];        // 16B-aligned
  float* Vv = &T[64 * 65 + 64];   // 16B-aligned
  const float4* Uv4 = (const float4*)Uv;
  const float4* Vv4 = (const float4*)Vv;
  Vv[l] = 1.0f;
  __syncthreads();

  float u = 1.0f;
  for (int it = 0; it < SINK_ITERS; ++it) {
    float s0 = 0.f, s1 = 0.f, s2 = 0.f, s3 = 0.f;
    #pragma unroll
    for (int q = 0; q < 16; ++q) {
      float4 v = Vv4[q];
      s0 = fmaf(K[4*q+0], v.x, s0);
      s1 = fmaf(K[4*q+1], v.y, s1);
      s2 = fmaf(K[4*q+2], v.z, s2);
      s3 = fmaf(K[4*q+3], v.w, s3);
    }
    u = 1.0f / ((s0 + s1) + (s2 + s3));
    __syncthreads();
    Uv[l] = u;
    __syncthreads();
    float c0 = 0.f, c1 = 0.f, c2 = 0.f, c3 = 0.f;
    #pragma unroll
    for (int q = 0; q < 16; ++q) {
      float4 uu = Uv4[q];
      c0 = fmaf(KT[4*q+0], uu.x, c0);
      c1 = fmaf(KT[4*q+1], uu.y, c1);
      c2 = fmaf(KT[4*q+2], uu.z, c2);
      c3 = fmaf(KT[4*q+3], uu.w, c3);
    }
    float v = 1.0f / ((c0 + c1) + (c2 + c3));
    __syncthreads();
    Vv[l] = v;
    __syncthreads();
  }

  #pragma unroll
  for (int j = 0; j < 64; ++j) T[l * 65 + j] = u * K[j] * Vv[j];
  __syncthreads();

  #pragma unroll
  for (int s = 0; s < 2; ++s)
    #pragma unroll
    for (int t = 0; t < 4; ++t) {
      union { unsigned short us[8]; bf16x8 v; } buf;
      #pragma unroll
      for (int j = 0; j < 8; ++j)
        buf.us[j] = f2bf(T[(s*32 + ((l >> 4) << 3) + j) * 65 + t*16 + (l & 15)]);
      *(bf16x8*)(Pfrag + (((s*4 + t) * 64 + l) << 3)) = buf.v;
    }

  if (l < NLAYERS) {
    float w0 = weights[l];
    float w1 = 1.0f - w0;
    float a  = biases[l];
    float e0, e1, cl, cg, sgn;
    if (fabsf(a - 0.5f) < EPS) {
      e0 = 0.f; e1 = 0.f; cl = 1.f; cg = 0.f; sgn = 1.f;   // pure linear
    } else {
      float ae;
      if (a < 0.5f) { sgn = -1.f; ae = fminf(fmaxf(1.0f - a, -1.0f + EPS), 2.0f - EPS); }
      else          { sgn =  1.f; ae = a; }
      float pp = sqrtf(3.0f / fmaxf(2.0f - ae, EPS)) - 1.0f;
      if (ae >= 0.75f) { cl = 0.0f;            cg = 1.0f; }
      else             { cl = 3.0f - 4.0f*ae;  cg = 4.0f*ae - 2.0f; }
      e0 = 2.0f * w0 * pp;
      e1 = 2.0f * w1 * pp;
    }
    float* Lr = layers + l * 8;
    Lr[0] = w0; Lr[1] = w1; Lr[2] = e0; Lr[3] = e1;
    Lr[4] = cl; Lr[5] = cg; Lr[6] = a;  Lr[7] = sgn;
  }
}

// ---------------------------------------------------------------------------
// F step: fully BRANCHLESS, register-only, hardware log2/exp2.
//   x' = sgn*x + off (off = (1-sgn)/2) handles the De Morgan reflection;
//   mode0 folds into cl=1,cg=0,e0=e1=0 (g==exp2(0)==1, cg*g==0 -> r=lin).
//   ~15 straight-line VALU / step, zero exec-mask manipulation.
// ---------------------------------------------------------------------------
__device__ __forceinline__ float F_step(float st, float leaf,
                                        float4 p0, float4 p1) {
  const float w0 = p0.x, w1 = p0.y, e0 = p0.z, e1 = p0.w;
  const float cl = p1.x, cg = p1.y, av = p1.z, sgn = p1.w;
  const float off = fmaf(-0.5f, sgn, 0.5f);
  float xx = fminf(fmaxf(st,   EPS), 1.0f - EPS);
  float yy = fminf(fmaxf(leaf, EPS), 1.0f - EPS);
  xx = fmaf(sgn, xx, off);
  yy = fmaf(sgn, yy, off);
  float lin = fmaf(w0, xx, w1 * yy);
  float g   = fast_exp2(fmaf(e0, fast_log2(xx), e1 * fast_log2(yy)));
  float r   = fmaf(cl, lin, cg * g);
  r = fmaf(sgn, r, off);
  return (r != r) ? av : r;   // NaN fallback (provably never fires; kept)
}

// ---------------------------------------------------------------------------
// Kernel 2 (R13): R11's structure verbatim (best measured: 125.3) with the
// branchless chain. Swapped-operand MFMA -> transposed D; fp32 leaf buffer
// stride 36; two n-halves; zero barriers (all wave-local DS ordering).
// ---------------------------------------------------------------------------
__global__ __launch_bounds__(256, 2) void scan_kernel(
    const float* __restrict__ x,
    const unsigned short* __restrict__ Pfrag,
    const float* __restrict__ layers,
    float* __restrict__ out) {
  __shared__ float Lv[256 * 36];
  const int tid = threadIdx.x;
  const int w = tid >> 6, l = tid & 63;
  const int q = l >> 4, c = l & 15;
  const size_t rowbase = (size_t)blockIdx.x << 8;   // 256 rows per block
  const float4* Lp4 = (const float4*)layers;        // uniform -> s_load_dwordx4

  // ---- B fragments (Aop after swap): Pfrag, coalesced, L2-hot.
  bf16x8 Bf[2][4];
  #pragma unroll
  for (int s = 0; s < 2; ++s)
    #pragma unroll
    for (int t = 0; t < 4; ++t)
      Bf[s][t] = *(const bf16x8*)(Pfrag + (((s*4 + t) * 64 + l) << 3));

  // ---- A fragments (Bop after swap): transient per-tile gather from x.
  bf16x8 Af[4][2];
  #pragma unroll
  for (int i = 0; i < 4; ++i) {
    const float* rp = x + (rowbase + (w << 6) + (i << 4) + c) * 64 + (q << 3);
    float4 a0 = *(const float4*)(rp);
    float4 a1 = *(const float4*)(rp + 4);
    float4 b0 = *(const float4*)(rp + 32);
    float4 b1 = *(const float4*)(rp + 36);
    Af[i][0] = pack8(a0, a1);
    Af[i][1] = pack8(b0, b1);
  }

  float st = 0.f;
  #pragma unroll
  for (int half = 0; half < 2; ++half) {
    // ---- GEMM^T: leaf-tiles {2*half, 2*half+1} x row-tiles 0..3.
    // Lane l gets leaves (lt*16 + q*4 .. +3) of batch row (rt*16 + c):
    // one float4 LDS write per D-tile.
    #pragma unroll
    for (int rt = 0; rt < 4; ++rt) {
      #pragma unroll
      for (int lt = 0; lt < 2; ++lt) {
        f32x4 acc = {0.f, 0.f, 0.f, 0.f};
        acc = __builtin_amdgcn_mfma_f32_16x16x32_bf16(Bf[0][(half<<1)+lt], Af[rt][0], acc, 0, 0, 0);
        acc = __builtin_amdgcn_mfma_f32_16x16x32_bf16(Bf[1][(half<<1)+lt], Af[rt][1], acc, 0, 0, 0);
        const int row  = (w << 6) + (rt << 4) + c;     // block-local batch row
        const int nloc = (lt << 4) + (q << 2);         // local leaf 0..28
        *(f32x4*)&Lv[row * 36 + nloc] = acc;           // ds_write_b128, 2-way
      }
    }
    // ---- own row -> registers (8x ds_read_b128; wave-local DS ordering).
    f32x4 Lf[8];
    #pragma unroll
    for (int i = 0; i < 8; ++i)
      Lf[i] = *(f32x4*)&Lv[tid * 36 + (i << 2)];

    // ---- branchless register-only F chain.
    if (half == 0) {
      st = Lf[0][0];
      #pragma unroll
      for (int j = 1; j < 32; ++j)
        st = F_step(st, Lf[j >> 2][j & 3],
                    Lp4[(j - 1) * 2], Lp4[(j - 1) * 2 + 1]);
    } else {
      #pragma unroll
      for (int j = 32; j < 64; ++j) {
        const int jl = j - 32;
        st = F_step(st, Lf[jl >> 2][jl & 3],
                    Lp4[(j - 1) * 2], Lp4[(j - 1) * 2 + 1]);
      }
    }
  }

  out[rowbase + tid] = st;
}

// ---------------------------------------------------------------------------
extern "C" void kernel_launch(void* const* d_in, const int* in_sizes, int n_in,
                              void* d_out, int out_size, void* d_ws, size_t ws_size,
                              hipStream_t stream) {
  const float* x       = (const float*)d_in[0];
  const float* logits  = (const float*)d_in[1];
  const float* weights = (const float*)d_in[2];
  const float* biases  = (const float*)d_in[3];
  float* out = (float*)d_out;

  unsigned short* Pfrag = (unsigned short*)d_ws;              // 8 KB
  float* layers = (float*)((char*)d_ws + 8 * 64 * 8 * sizeof(unsigned short));

  const int batch = out_size;  // 262144

  hipLaunchKernelGGL(sinkhorn_kernel, dim3(1), dim3(64), 0, stream,
                     logits, weights, biases, Pfrag, layers);
  hipLaunchKernelGGL(scan_kernel, dim3(batch / 256), dim3(256), 0, stream,
                     x, Pfrag, layers, out);
}

// Round 14
// 119.797 us; speedup vs baseline: 1.0601x; 1.0190x over previous
//
#include <hip/hip_runtime.h>
#include <hip/hip_bf16.h>
#include <math.h>

#define EPS 1e-6f
#define N 64          // INPUT_SIZE == NUM_LEAVES
#define NLAYERS 63
#define SINK_ITERS 20
#define LOG2E 1.4426950408889634f

typedef __attribute__((ext_vector_type(8))) short bf16x8;   // 8 bf16 = 4 VGPRs
typedef __attribute__((ext_vector_type(4))) float f32x4;    // MFMA C/D

// Hardware transcendentals: single v_log_f32 / v_exp_f32. Inputs clamped to
// [EPS, 1-EPS] (normal range) -> no denormal/edge fixup needed.
__device__ __forceinline__ float fast_log2(float v) {
#if __has_builtin(__builtin_amdgcn_logf)
  return __builtin_amdgcn_logf(v);
#else
  return log2f(v);
#endif
}
__device__ __forceinline__ float fast_exp2(float v) {
#if __has_builtin(__builtin_amdgcn_exp2f)
  return __builtin_amdgcn_exp2f(v);
#else
  return exp2f(v);
#endif
}

// fp32 -> bf16 round-to-nearest-even (bit pattern in ushort)
__device__ __forceinline__ unsigned short f2bf(float f) {
  unsigned int u = __float_as_uint(f);
  return (unsigned short)((u + 0x7FFFu + ((u >> 16) & 1u)) >> 16);
}

__device__ __forceinline__ bf16x8 pack8(float4 a, float4 b) {
  union { unsigned short us[8]; bf16x8 v; } u;
  u.us[0] = f2bf(a.x); u.us[1] = f2bf(a.y);
  u.us[2] = f2bf(a.z); u.us[3] = f2bf(a.w);
  u.us[4] = f2bf(b.x); u.us[5] = f2bf(b.y);
  u.us[6] = f2bf(b.z); u.us[7] = f2bf(b.w);
  return u.v;
}

// ---------------------------------------------------------------------------
// Kernel 1: Sinkhorn (scaling-vector form, single wave) + P -> MFMA B-fragment
// precompute (bf16) + per-layer scan constants (branchless encoding).
// Layer params [63][8]: w0, w1, e0, e1, cl, cg, a(unused now), sgn.
//   sgn=+1 (no reflection) / sgn=-1 (De Morgan); off=(1-sgn)/2.
//   mode0 (|a-0.5|<eps) folds to cl=1, cg=0, e0=e1=0 (g==1 exactly).
// B-frag for mfma_f32_16x16x32_bf16: lane l holds
// B[k = s*32 + (l>>4)*8 + j][n = t*16 + (l&15)], j=0..7.   (Validated R6-R13.)
// ---------------------------------------------------------------------------
__global__ __launch_bounds__(64) void sinkhorn_kernel(
    const float* __restrict__ logits,
    const float* __restrict__ weights,
    const float* __restrict__ biases,
    unsigned short* __restrict__ Pfrag,  // [8][64][8] bf16
    float* __restrict__ layers) {        // [63][8]
  __shared__ float T[64 * 65 + 128];
  const int l = threadIdx.x;

  float K[64];
  {
    const float4* lr = (const float4*)(logits + (l << 6));
    #pragma unroll
    for (int q = 0; q < 16; ++q) {
      float4 t = lr[q];
      K[4*q+0] = fast_exp2(t.x * LOG2E);
      K[4*q+1] = fast_exp2(t.y * LOG2E);
      K[4*q+2] = fast_exp2(t.z * LOG2E);
      K[4*q+3] = fast_exp2(t.w * LOG2E);
    }
  }
  #pragma unroll
  for (int j = 0; j < 64; ++j) T[l * 65 + j] = K[j];
  __syncthreads();
  float KT[64];
  #pragma unroll
  for (int k = 0; k < 64; ++k) KT[k] = T[k * 65 + l];
  __syncthreads();

  float* Uv = &T[64 * 65];        // 16B-aligned
  float* Vv = &T[64 * 65 + 64];   // 16B-aligned
  const float4* Uv4 = (const float4*)Uv;
  const float4* Vv4 = (const float4*)Vv;
  Vv[l] = 1.0f;
  __syncthreads();

  float u = 1.0f;
  for (int it = 0; it < SINK_ITERS; ++it) {
    float s0 = 0.f, s1 = 0.f, s2 = 0.f, s3 = 0.f;
    #pragma unroll
    for (int q = 0; q < 16; ++q) {
      float4 v = Vv4[q];
      s0 = fmaf(K[4*q+0], v.x, s0);
      s1 = fmaf(K[4*q+1], v.y, s1);
      s2 = fmaf(K[4*q+2], v.z, s2);
      s3 = fmaf(K[4*q+3], v.w, s3);
    }
    u = 1.0f / ((s0 + s1) + (s2 + s3));
    __syncthreads();
    Uv[l] = u;
    __syncthreads();
    float c0 = 0.f, c1 = 0.f, c2 = 0.f, c3 = 0.f;
    #pragma unroll
    for (int q = 0; q < 16; ++q) {
      float4 uu = Uv4[q];
      c0 = fmaf(KT[4*q+0], uu.x, c0);
      c1 = fmaf(KT[4*q+1], uu.y, c1);
      c2 = fmaf(KT[4*q+2], uu.z, c2);
      c3 = fmaf(KT[4*q+3], uu.w, c3);
    }
    float v = 1.0f / ((c0 + c1) + (c2 + c3));
    __syncthreads();
    Vv[l] = v;
    __syncthreads();
  }

  #pragma unroll
  for (int j = 0; j < 64; ++j) T[l * 65 + j] = u * K[j] * Vv[j];
  __syncthreads();

  #pragma unroll
  for (int s = 0; s < 2; ++s)
    #pragma unroll
    for (int t = 0; t < 4; ++t) {
      union { unsigned short us[8]; bf16x8 v; } buf;
      #pragma unroll
      for (int j = 0; j < 8; ++j)
        buf.us[j] = f2bf(T[(s*32 + ((l >> 4) << 3) + j) * 65 + t*16 + (l & 15)]);
      *(bf16x8*)(Pfrag + (((s*4 + t) * 64 + l) << 3)) = buf.v;
    }

  if (l < NLAYERS) {
    float w0 = weights[l];
    float w1 = 1.0f - w0;
    float a  = biases[l];
    float e0, e1, cl, cg, sgn;
    if (fabsf(a - 0.5f) < EPS) {
      e0 = 0.f; e1 = 0.f; cl = 1.f; cg = 0.f; sgn = 1.f;   // pure linear
    } else {
      float ae;
      if (a < 0.5f) { sgn = -1.f; ae = fminf(fmaxf(1.0f - a, -1.0f + EPS), 2.0f - EPS); }
      else          { sgn =  1.f; ae = a; }
      float pp = sqrtf(3.0f / fmaxf(2.0f - ae, EPS)) - 1.0f;
      if (ae >= 0.75f) { cl = 0.0f;            cg = 1.0f; }
      else             { cl = 3.0f - 4.0f*ae;  cg = 4.0f*ae - 2.0f; }
      e0 = 2.0f * w0 * pp;
      e1 = 2.0f * w1 * pp;
    }
    float* Lr = layers + l * 8;
    Lr[0] = w0; Lr[1] = w1; Lr[2] = e0; Lr[3] = e1;
    Lr[4] = cl; Lr[5] = cg; Lr[6] = a;  Lr[7] = sgn;
  }
}

// ---------------------------------------------------------------------------
// Kernel 2 (R14): R13 + CRITICAL-PATH SPLIT.
// Leaf-side terms (clamp, reflect, log2, *e1, *w1) depend only on the leaf
// and layer constants -> precomputed for the whole half in an ILP-rich block.
// Dependent chain per step shrinks to 7 ops:
//   clamp(2) -> reflect(1) -> v_log(1) -> fmaf(1) -> v_exp(1) -> fmaf(1)
//   -> reflect(1); lin runs in parallel off xx.
// NaN select dropped: inputs clamped to [EPS,1-EPS] => g in [2^-30,1], every
// intermediate finite; reference's isnan-fallback is provably identity here.
// ---------------------------------------------------------------------------
__global__ __launch_bounds__(256, 2) void scan_kernel(
    const float* __restrict__ x,
    const unsigned short* __restrict__ Pfrag,
    const float* __restrict__ layers,
    float* __restrict__ out) {
  __shared__ float Lv[256 * 36];
  const int tid = threadIdx.x;
  const int w = tid >> 6, l = tid & 63;
  const int q = l >> 4, c = l & 15;
  const size_t rowbase = (size_t)blockIdx.x << 8;   // 256 rows per block
  const float4* Lp4 = (const float4*)layers;        // uniform -> s_load_dwordx4

  // ---- B fragments (Aop after swap): Pfrag, coalesced, L2-hot.
  bf16x8 Bf[2][4];
  #pragma unroll
  for (int s = 0; s < 2; ++s)
    #pragma unroll
    for (int t = 0; t < 4; ++t)
      Bf[s][t] = *(const bf16x8*)(Pfrag + (((s*4 + t) * 64 + l) << 3));

  // ---- A fragments (Bop after swap): transient per-tile gather from x.
  bf16x8 Af[4][2];
  #pragma unroll
  for (int i = 0; i < 4; ++i) {
    const float* rp = x + (rowbase + (w << 6) + (i << 4) + c) * 64 + (q << 3);
    float4 a0 = *(const float4*)(rp);
    float4 a1 = *(const float4*)(rp + 4);
    float4 b0 = *(const float4*)(rp + 32);
    float4 b1 = *(const float4*)(rp + 36);
    Af[i][0] = pack8(a0, a1);
    Af[i][1] = pack8(b0, b1);
  }

  float st = 0.f;
  #pragma unroll
  for (int half = 0; half < 2; ++half) {
    // ---- GEMM^T: leaf-tiles {2*half, 2*half+1} x row-tiles 0..3.
    #pragma unroll
    for (int rt = 0; rt < 4; ++rt) {
      #pragma unroll
      for (int lt = 0; lt < 2; ++lt) {
        f32x4 acc = {0.f, 0.f, 0.f, 0.f};
        acc = __builtin_amdgcn_mfma_f32_16x16x32_bf16(Bf[0][(half<<1)+lt], Af[rt][0], acc, 0, 0, 0);
        acc = __builtin_amdgcn_mfma_f32_16x16x32_bf16(Bf[1][(half<<1)+lt], Af[rt][1], acc, 0, 0, 0);
        const int row  = (w << 6) + (rt << 4) + c;     // block-local batch row
        const int nloc = (lt << 4) + (q << 2);         // local leaf 0..28
        *(f32x4*)&Lv[row * 36 + nloc] = acc;           // ds_write_b128, 2-way
      }
    }
    // ---- own row -> registers (8x ds_read_b128; wave-local DS ordering).
    f32x4 Lf[8];
    #pragma unroll
    for (int i = 0; i < 8; ++i)
      Lf[i] = *(f32x4*)&Lv[tid * 36 + (i << 2)];

    const int j0 = (half == 0) ? 1 : 32;    // first step index this half
    const int nst = (half == 0) ? 31 : 32;  // steps this half

    // ---- leaf-side precompute (independent of st; pure ILP).
    float ylin[32], ylog[32];
    #pragma unroll
    for (int k = 0; k < 32; ++k) {
      if (k < nst) {
        const int j = j0 + k;                       // global step index
        const int jl = j - (half << 5);             // local leaf index
        float4 p0 = Lp4[(j - 1) * 2];               // w0,w1,e0,e1
        float4 p1 = Lp4[(j - 1) * 2 + 1];           // cl,cg,a,sgn
        const float sgn = p1.w;
        const float off = fmaf(-0.5f, sgn, 0.5f);
        float yy = fminf(fmaxf(Lf[jl >> 2][jl & 3], EPS), 1.0f - EPS);
        float yr = fmaf(sgn, yy, off);
        ylin[k] = p0.y * yr;                        // w1 * y'
        ylog[k] = p0.w * fast_log2(yr);             // e1 * log2(y')
      }
    }

    // ---- dependent chain: 7 ops/step on the critical path.
    if (half == 0) st = Lf[0][0];
    #pragma unroll
    for (int k = 0; k < 32; ++k) {
      if (k < nst) {
        const int j = j0 + k;
        float4 p0 = Lp4[(j - 1) * 2];
        float4 p1 = Lp4[(j - 1) * 2 + 1];
        const float sgn = p1.w;
        const float off = fmaf(-0.5f, sgn, 0.5f);
        float xx = fminf(fmaxf(st, EPS), 1.0f - EPS);
        xx = fmaf(sgn, xx, off);
        float lin = fmaf(p0.x, xx, ylin[k]);        // parallel to log/exp
        float g   = fast_exp2(fmaf(p0.z, fast_log2(xx), ylog[k]));
        float r   = fmaf(p1.x, lin, p1.y * g);
        st = fmaf(sgn, r, off);
      }
    }
  }

  out[rowbase + tid] = st;
}

// ---------------------------------------------------------------------------
extern "C" void kernel_launch(void* const* d_in, const int* in_sizes, int n_in,
                              void* d_out, int out_size, void* d_ws, size_t ws_size,
                              hipStream_t stream) {
  const float* x       = (const float*)d_in[0];
  const float* logits  = (const float*)d_in[1];
  const float* weights = (const float*)d_in[2];
  const float* biases  = (const float*)d_in[3];
  float* out = (float*)d_out;

  unsigned short* Pfrag = (unsigned short*)d_ws;              // 8 KB
  float* layers = (float*)((char*)d_ws + 8 * 64 * 8 * sizeof(unsigned short));

  const int batch = out_size;  // 262144

  hipLaunchKernelGGL(sinkhorn_kernel, dim3(1), dim3(64), 0, stream,
                     logits, weights, biases, Pfrag, layers);
  hipLaunchKernelGGL(scan_kernel, dim3(batch / 256), dim3(256), 0, stream,
                     x, Pfrag, layers, out);
}